// Round 1
// baseline (56.233 us; speedup 1.0000x reference)
//
#include <hip/hip_runtime.h>
#include <math.h>

#define D 64
#define MAXP 145          // pos_emb rows (max n)
#define EPSF 1e-5f
#define NPAR 130048

// ---- workspace layout (floats) ----
// kpos [MAXP][64]           @ 0
// vpos [MAXP][64]           @ MAXP*64
// q0[64] kcls[64] vcls[64] uk[64] uv[64]   @ 2*MAXP*64
// beta [MAXP][4]            @ 2*MAXP*64 + 320
// alpha[4] gamma[4]         @ 2*MAXP*64 + 320 + MAXP*4
#define WS_KPOS 0
#define WS_VPOS (MAXP*64)
#define WS_Q0   (2*MAXP*64)
#define WS_KCLS (WS_Q0+64)
#define WS_VCLS (WS_Q0+128)
#define WS_UK   (WS_Q0+192)
#define WS_UV   (WS_Q0+256)
#define WS_BETA (WS_Q0+320)
#define WS_ALGA (WS_BETA+MAXP*4)

// K1: blocks 0..144 -> kpos[j], vpos[j]; block 145 -> q0,kcls,vcls,uk,uv
__global__ __launch_bounds__(64) void k_pre(const float* __restrict__ pe,
                                            const float* __restrict__ ct,
                                            const float* __restrict__ W,   // in_proj_w (192,64)
                                            const float* __restrict__ bq,  // in_proj_b (192)
                                            float* __restrict__ ws)
{
    int j = blockIdx.x;
    int o = threadIdx.x;   // 0..63
    if (j < MAXP) {
        const float* p  = pe + j*64;
        const float* wk = W + (64 + o)*64;
        const float* wv = W + (128 + o)*64;
        float sk = bq[64 + o], sv = bq[128 + o];
        for (int d = 0; d < 64; ++d) { float pd = p[d]; sk += wk[d]*pd; sv += wv[d]*pd; }
        ws[WS_KPOS + j*64 + o] = sk;
        ws[WS_VPOS + j*64 + o] = sv;
    } else {
        const float* wq = W + o*64;
        const float* wk = W + (64 + o)*64;
        const float* wv = W + (128 + o)*64;
        float sq = bq[o], sk = bq[64+o], sv = bq[128+o], suk = 0.f, suv = 0.f;
        for (int d = 0; d < 64; ++d) {
            float c = ct[d];
            sq += wq[d]*c; sk += wk[d]*c; sv += wv[d]*c;
            suk += wk[d];  suv += wv[d];
        }
        ws[WS_Q0 + o]   = sq;
        ws[WS_KCLS + o] = sk;
        ws[WS_VCLS + o] = sv;
        ws[WS_UK + o]   = suk;
        ws[WS_UV + o]   = suv;
    }
}

// K2: beta[j][h] = q0_h . kpos_h[j]; alpha[h] = q0_h . uk_h; gamma[h] = q0_h . kcls_h
__global__ __launch_bounds__(256) void k_beta(float* __restrict__ ws)
{
    const float* kpos = ws + WS_KPOS;
    const float* q0   = ws + WS_Q0;
    const float* kcls = ws + WS_KCLS;
    const float* uk   = ws + WS_UK;
    float* beta = ws + WS_BETA;
    float* alga = ws + WS_ALGA;
    int tid = threadIdx.x;
    for (int i = tid; i < MAXP*4; i += 256) {
        int j = i >> 2, h = i & 3;
        float s = 0.f;
        for (int e = 0; e < 16; ++e) s += q0[h*16+e] * kpos[j*64 + h*16 + e];
        beta[i] = s;
    }
    if (tid < 4) {
        int h = tid;
        float a = 0.f, g = 0.f;
        for (int e = 0; e < 16; ++e) {
            a += q0[h*16+e] * uk[h*16+e];
            g += q0[h*16+e] * kcls[h*16+e];
        }
        alga[h]     = a;
        alga[4 + h] = g;
    }
}

// K3: one block (1 wave, 64 threads) per sequence.
__global__ __launch_bounds__(64) void k_main(
    const float* __restrict__ x,
    const float* __restrict__ ct,
    const float* __restrict__ Wo,  const float* __restrict__ bo,
    const float* __restrict__ L1w, const float* __restrict__ b1,
    const float* __restrict__ L2w, const float* __restrict__ b2,
    const float* __restrict__ ln1w, const float* __restrict__ ln1b,
    const float* __restrict__ ln2w, const float* __restrict__ ln2b,
    const float* __restrict__ ws,
    float* __restrict__ out)
{
    const float* vpos = ws + WS_VPOS;
    const float* vcls = ws + WS_VCLS;
    const float* uv   = ws + WS_UV;
    const float* beta = ws + WS_BETA;
    const float* alga = ws + WS_ALGA;

    int bid = blockIdx.x;
    int start, L, kno, kg_off, b, k;
    if (bid < 1024)      { start = 0;     L = 72;  kno = 256; kg_off = 0;   b = bid >> 8;           k = bid & 255; }
    else if (bid < 2048) { int m = bid-1024; start = 18688; L = 144; kno = 256; kg_off = 256; b = m >> 8; k = m & 255; }
    else                 { int m = bid-2048; start = 55808; L = 144; kno = 512; kg_off = 512; b = m >> 9; k = m & 511; }
    const int n = L + 1;     // non-cls tokens
    const int S = n + 1;     // sequence length incl. cls

    __shared__ float w_s[MAXP];
    __shared__ float attn[4][MAXP + 1];
    __shared__ float o_s[64];
    __shared__ float h1_s[64];
    __shared__ float r_s[96];

    const int lane = threadIdx.x;
    const float* xb = x + (size_t)b * NPAR;

    // load scalar params w[0..n)
    for (int j = lane; j < L; j += 64) w_s[j] = xb[start + k*L + j];
    if (lane == 0) w_s[L] = xb[start + kno*L + k];
    __syncthreads();

    // scores (already /4)
    for (int i = lane; i < 4*S; i += 64) {
        int h = i / S, s = i - h*S;
        float sc;
        if (s == 0) sc = alga[4 + h];
        else        { int j = s - 1; sc = alga[h] * w_s[j] + beta[j*4 + h]; }
        attn[h][s] = sc * 0.25f;
    }
    __syncthreads();

    // softmax per head (each lane only touches its own strided subset in LDS)
    for (int h = 0; h < 4; ++h) {
        float m = -1e30f;
        for (int s = lane; s < S; s += 64) m = fmaxf(m, attn[h][s]);
        for (int off = 32; off; off >>= 1) m = fmaxf(m, __shfl_xor(m, off));
        float sum = 0.f;
        for (int s = lane; s < S; s += 64) { float e = expf(attn[h][s] - m); attn[h][s] = e; sum += e; }
        for (int off = 32; off; off >>= 1) sum += __shfl_xor(sum, off);
        float inv = 1.f / sum;
        for (int s = lane; s < S; s += 64) attn[h][s] *= inv;
    }
    __syncthreads();

    // wsum[h] = sum_{s>=1} a[s]*w[s-1]
    float wsum[4], a0[4];
    for (int h = 0; h < 4; ++h) {
        float s = 0.f;
        for (int t = lane; t < n; t += 64) s += attn[h][t+1] * w_s[t];
        for (int off = 32; off; off >>= 1) s += __shfl_xor(s, off);
        wsum[h] = s;
        a0[h]   = attn[h][0];
    }

    // o[d] = wsum_h*uv[d] + a0_h*vcls[d] + sum_j a[j+1]*vpos[j][d]
    const int d = lane;
    const int h = d >> 4;
    float acc = wsum[h]*uv[d] + a0[h]*vcls[d];
    for (int j = 0; j < n; ++j) acc += attn[h][j+1] * vpos[j*64 + d];
    o_s[d] = acc;
    __syncthreads();

    // out proj + residual(cls) + LN1
    float op = bo[d];
    {
        const float* wr = Wo + d*64;
        for (int e = 0; e < 64; ++e) op += wr[e] * o_s[e];
    }
    float pre = ct[d] + op;
    float mu = pre;
    for (int off = 32; off; off >>= 1) mu += __shfl_xor(mu, off);
    mu *= (1.f/64.f);
    float dv = pre - mu;
    float var = dv*dv;
    for (int off = 32; off; off >>= 1) var += __shfl_xor(var, off);
    var *= (1.f/64.f);
    float h1 = dv * rsqrtf(var + EPSF) * ln1w[d] + ln1b[d];
    h1_s[d] = h1;
    __syncthreads();

    // FF1 (96 outputs) + relu
    for (int f = lane; f < 96; f += 64) {
        float s = b1[f];
        const float* r1 = L1w + f*64;
        for (int e = 0; e < 64; ++e) s += r1[e] * h1_s[e];
        r_s[f] = fmaxf(s, 0.f);
    }
    __syncthreads();

    // FF2 + residual + LN2
    float f2 = b2[d];
    {
        const float* r2 = L2w + d*96;
        for (int e = 0; e < 96; ++e) f2 += r2[e] * r_s[e];
    }
    float pre2 = h1 + f2;
    float mu2 = pre2;
    for (int off = 32; off; off >>= 1) mu2 += __shfl_xor(mu2, off);
    mu2 *= (1.f/64.f);
    float dv2 = pre2 - mu2;
    float var2 = dv2*dv2;
    for (int off = 32; off; off >>= 1) var2 += __shfl_xor(var2, off);
    var2 *= (1.f/64.f);
    float y = dv2 * rsqrtf(var2 + EPSF) * ln2w[d] + ln2b[d];

    const int kg = kg_off + k;
    float* po = out + ((size_t)b * 1024 + kg) * 128;
    po[d]      = y;
    po[64 + d] = y;   // tile (1,1,2)
}

extern "C" void kernel_launch(void* const* d_in, const int* in_sizes, int n_in,
                              void* d_out, int out_size, void* d_ws, size_t ws_size,
                              hipStream_t stream) {
    const float* x    = (const float*)d_in[0];
    const float* pe   = (const float*)d_in[1];
    const float* ct   = (const float*)d_in[2];
    const float* Wq   = (const float*)d_in[3];   // in_proj_w (192,64)
    const float* bq   = (const float*)d_in[4];   // in_proj_b (192)
    const float* Wo   = (const float*)d_in[5];   // out_proj_w (64,64)
    const float* bo   = (const float*)d_in[6];
    const float* L1w  = (const float*)d_in[7];   // (96,64)
    const float* b1   = (const float*)d_in[8];
    const float* L2w  = (const float*)d_in[9];   // (64,96)
    const float* b2   = (const float*)d_in[10];
    const float* ln1w = (const float*)d_in[11];
    const float* ln1b = (const float*)d_in[12];
    const float* ln2w = (const float*)d_in[13];
    const float* ln2b = (const float*)d_in[14];
    float* out = (float*)d_out;
    float* ws  = (float*)d_ws;

    k_pre <<<MAXP + 1, 64, 0, stream>>>(pe, ct, Wq, bq, ws);
    k_beta<<<1, 256, 0, stream>>>(ws);
    k_main<<<4096, 64, 0, stream>>>(x, ct, Wo, bo, L1w, b1, L2w, b2,
                                    ln1w, ln1b, ln2w, ln2b, ws, out);
}

// Round 2
// 55.578 us; speedup vs baseline: 1.0118x; 1.0118x over previous
//
#include <hip/hip_runtime.h>
#include <math.h>

#define MAXP 145          // max token count (ks*cin max) = 144, +1 bias token
#define PJ   148          // padded vposT row length (multiple of 4)
#define EPSF 1e-5f
#define NPAR 130048

// ---- workspace layout (floats) ----
#define WS_VPOST 0                      // [64][PJ]  vposT[d][j] = vpos[j][d], cols >=MAXP zeroed
#define WS_VCLS  (64*PJ)                // [64]
#define WS_UV    (WS_VCLS+64)           // [64]
#define WS_BETA  (WS_UV+64)             // betaT [4][152]
#define WS_ALGA  (WS_BETA+4*152)        // alpha[4], gamma[4]

// K1: blocks 0..144 -> vposT col j, betaT[.][j]; block 145 -> vcls, uv, alpha, gamma, zero-pad
__global__ __launch_bounds__(64) void k_pre(const float* __restrict__ pe,
                                            const float* __restrict__ ct,
                                            const float* __restrict__ W,   // in_proj_w (192,64)
                                            const float* __restrict__ bq,  // in_proj_b (192)
                                            float* __restrict__ ws)
{
    const int j = blockIdx.x;
    const int o = threadIdx.x;   // 0..63
    const float4* wq4 = (const float4*)(W + o*64);
    const float4* wk4 = (const float4*)(W + (64 + o)*64);
    const float4* wv4 = (const float4*)(W + (128 + o)*64);
    const float4* ct4 = (const float4*)ct;

    if (j < MAXP) {
        const float4* p4 = (const float4*)(pe + j*64);
        float sk = bq[64 + o], sv = bq[128 + o], sq = bq[o];
        #pragma unroll
        for (int e = 0; e < 16; ++e) {
            float4 k4 = wk4[e], v4 = wv4[e], q4 = wq4[e], pp = p4[e], cc = ct4[e];
            sk += k4.x*pp.x + k4.y*pp.y + k4.z*pp.z + k4.w*pp.w;
            sv += v4.x*pp.x + v4.y*pp.y + v4.z*pp.z + v4.w*pp.w;
            sq += q4.x*cc.x + q4.y*cc.y + q4.z*cc.z + q4.w*cc.w;
        }
        ws[WS_VPOST + o*PJ + j] = sv;
        // betaT[h][j] = sum over lanes of head h of q0[o]*kpos_j[o]
        float r = sq * sk;
        for (int off = 1; off < 16; off <<= 1) r += __shfl_xor(r, off);
        if ((o & 15) == 0) ws[WS_BETA + (o >> 4)*152 + j] = r;
    } else {
        float sq = bq[o], sk = bq[64 + o], sv = bq[128 + o], suk = 0.f, suv = 0.f;
        #pragma unroll
        for (int e = 0; e < 16; ++e) {
            float4 k4 = wk4[e], v4 = wv4[e], q4 = wq4[e], cc = ct4[e];
            sq += q4.x*cc.x + q4.y*cc.y + q4.z*cc.z + q4.w*cc.w;
            sk += k4.x*cc.x + k4.y*cc.y + k4.z*cc.z + k4.w*cc.w;
            sv += v4.x*cc.x + v4.y*cc.y + v4.z*cc.z + v4.w*cc.w;
            suk += k4.x + k4.y + k4.z + k4.w;
            suv += v4.x + v4.y + v4.z + v4.w;
        }
        ws[WS_VCLS + o] = sv;
        ws[WS_UV + o]   = suv;
        // zero padding columns of vposT
        for (int jj = MAXP; jj < PJ; ++jj) ws[WS_VPOST + o*PJ + jj] = 0.f;
        // alpha[h] = head-sum q0*uk ; gamma[h] = head-sum q0*kcls
        float a = sq * suk, g = sq * sk;
        for (int off = 1; off < 16; off <<= 1) {
            a += __shfl_xor(a, off);
            g += __shfl_xor(g, off);
        }
        if ((o & 15) == 0) { ws[WS_ALGA + (o >> 4)] = a; ws[WS_ALGA + 4 + (o >> 4)] = g; }
    }
}

// K2: one block (1 wave, 64 threads) per sequence.
__global__ __launch_bounds__(64) void k_main(
    const float* __restrict__ x,
    const float* __restrict__ ct,
    const float* __restrict__ Wo,  const float* __restrict__ bo,
    const float* __restrict__ L1w, const float* __restrict__ b1,
    const float* __restrict__ L2w, const float* __restrict__ b2,
    const float* __restrict__ ln1w, const float* __restrict__ ln1b,
    const float* __restrict__ ln2w, const float* __restrict__ ln2b,
    const float* __restrict__ ws,
    float* __restrict__ out)
{
    const float* vposT = ws + WS_VPOST;
    const float* vcls  = ws + WS_VCLS;
    const float* uv    = ws + WS_UV;
    const float* betaT = ws + WS_BETA;
    const float* alga  = ws + WS_ALGA;

    int bid = blockIdx.x;
    int start, L, kno, kg_off, b, k;
    if (bid < 1024)      { start = 0;     L = 72;  kno = 256; kg_off = 0;   b = bid >> 8;           k = bid & 255; }
    else if (bid < 2048) { int m = bid-1024; start = 18688; L = 144; kno = 256; kg_off = 256; b = m >> 8; k = m & 255; }
    else                 { int m = bid-2048; start = 55808; L = 144; kno = 512; kg_off = 512; b = m >> 9; k = m & 511; }
    const int n  = L + 1;        // non-cls tokens
    const int S  = n + 1;        // sequence length incl. cls
    const int n4 = (n + 3) >> 2; // float4 chunks of attention row

    __shared__ float w_s[PJ];
    __shared__ float attn[4][152];
    __shared__ float att2[4][PJ];   // normalized, shifted (j = s-1), zero-padded
    __shared__ float a0_s[4];
    __shared__ float o_s[64];
    __shared__ float h1_s[64];
    __shared__ float r_s[96];

    const int lane = threadIdx.x;
    const float* xb = x + (size_t)b * NPAR;

    // scalar params: one float4 load + bias scalar
    if (lane * 4 < L) {
        float4 v = *(const float4*)(xb + start + (size_t)k * L + lane*4);
        *(float4*)(w_s + lane*4) = v;
    }
    if (lane == 0) w_s[L] = xb[start + (size_t)kno * L + k];
    __syncthreads();

    // scores (pre-scaled by 1/4)
    #pragma unroll
    for (int h = 0; h < 4; ++h) {
        const float alpha = alga[h];
        const float gam   = alga[4 + h];
        const float* bh   = betaT + h*152;
        for (int s = lane; s < S; s += 64) {
            float sc = (s == 0) ? gam : fmaf(alpha, w_s[s-1], bh[s-1]);
            attn[h][s] = sc * 0.25f;
        }
    }
    __syncthreads();

    // softmax per head -> att2 (shifted, normalized, zero-padded), a0_s
    #pragma unroll
    for (int h = 0; h < 4; ++h) {
        float m = -1e30f;
        for (int s = lane; s < S; s += 64) m = fmaxf(m, attn[h][s]);
        #pragma unroll
        for (int off = 32; off; off >>= 1) m = fmaxf(m, __shfl_xor(m, off));
        float sum = 0.f;
        for (int s = lane; s < S; s += 64) { float e = __expf(attn[h][s] - m); attn[h][s] = e; sum += e; }
        #pragma unroll
        for (int off = 32; off; off >>= 1) sum += __shfl_xor(sum, off);
        const float inv = 1.f / sum;
        for (int s = lane; s < S; s += 64) {
            float a = attn[h][s] * inv;
            if (s == 0) a0_s[h] = a;
            else        att2[h][s-1] = a;
        }
        for (int jj = n + lane; jj < n4*4; jj += 64) att2[h][jj] = 0.f;
    }
    __syncthreads();

    // wsum[h] = sum_j a[h][j]*w[j]
    float wsum[4];
    #pragma unroll
    for (int h = 0; h < 4; ++h) {
        float s = 0.f;
        for (int t = lane; t < n; t += 64) s += att2[h][t] * w_s[t];
        #pragma unroll
        for (int off = 32; off; off >>= 1) s += __shfl_xor(s, off);
        wsum[h] = s;
    }

    // o[d] = wsum_h*uv[d] + a0_h*vcls[d] + sum_j a[h][j]*vposT[d][j]   (float4 dot)
    const int d = lane;
    const int h = d >> 4;
    {
        const float4* vrow = (const float4*)(vposT + d*PJ);
        const float4* arow = (const float4*)(att2[h]);
        float ax = 0.f, ay = 0.f, az = 0.f, aw = 0.f;
        for (int t = 0; t < n4; ++t) {
            float4 a = arow[t], v = vrow[t];
            ax += a.x*v.x; ay += a.y*v.y; az += a.z*v.z; aw += a.w*v.w;
        }
        o_s[d] = (ax + ay) + (az + aw) + wsum[h]*uv[d] + a0_s[h]*vcls[d];
    }
    __syncthreads();

    // out proj + residual(cls) + LN1
    float op = bo[d];
    {
        const float4* wr = (const float4*)(Wo + d*64);
        const float4* os = (const float4*)o_s;
        float ax=0, ay=0, az=0, aw=0;
        #pragma unroll
        for (int e = 0; e < 16; ++e) {
            float4 w4 = wr[e], o4 = os[e];
            ax += w4.x*o4.x; ay += w4.y*o4.y; az += w4.z*o4.z; aw += w4.w*o4.w;
        }
        op += (ax + ay) + (az + aw);
    }
    float pre = ct[d] + op;
    float mu = pre;
    #pragma unroll
    for (int off = 32; off; off >>= 1) mu += __shfl_xor(mu, off);
    mu *= (1.f/64.f);
    float dv = pre - mu;
    float var = dv*dv;
    #pragma unroll
    for (int off = 32; off; off >>= 1) var += __shfl_xor(var, off);
    var *= (1.f/64.f);
    float h1 = dv * rsqrtf(var + EPSF) * ln1w[d] + ln1b[d];
    h1_s[d] = h1;
    __syncthreads();

    // FF1 (96 outputs) + relu
    {
        const float4* hv = (const float4*)h1_s;
        {
            const float4* r1 = (const float4*)(L1w + lane*64);
            float ax=0, ay=0, az=0, aw=0;
            #pragma unroll
            for (int e = 0; e < 16; ++e) {
                float4 w4 = r1[e], h4 = hv[e];
                ax += w4.x*h4.x; ay += w4.y*h4.y; az += w4.z*h4.z; aw += w4.w*h4.w;
            }
            r_s[lane] = fmaxf(b1[lane] + (ax+ay) + (az+aw), 0.f);
        }
        if (lane < 32) {
            const float4* r1 = (const float4*)(L1w + (64 + lane)*64);
            float ax=0, ay=0, az=0, aw=0;
            #pragma unroll
            for (int e = 0; e < 16; ++e) {
                float4 w4 = r1[e], h4 = hv[e];
                ax += w4.x*h4.x; ay += w4.y*h4.y; az += w4.z*h4.z; aw += w4.w*h4.w;
            }
            r_s[64 + lane] = fmaxf(b1[64 + lane] + (ax+ay) + (az+aw), 0.f);
        }
    }
    __syncthreads();

    // FF2 + residual + LN2
    float f2 = b2[d];
    {
        const float4* r2 = (const float4*)(L2w + d*96);
        const float4* rv = (const float4*)r_s;
        float ax=0, ay=0, az=0, aw=0;
        #pragma unroll
        for (int e = 0; e < 24; ++e) {
            float4 w4 = r2[e], h4 = rv[e];
            ax += w4.x*h4.x; ay += w4.y*h4.y; az += w4.z*h4.z; aw += w4.w*h4.w;
        }
        f2 += (ax + ay) + (az + aw);
    }
    float pre2 = h1 + f2;
    float mu2 = pre2;
    #pragma unroll
    for (int off = 32; off; off >>= 1) mu2 += __shfl_xor(mu2, off);
    mu2 *= (1.f/64.f);
    float dv2 = pre2 - mu2;
    float var2 = dv2*dv2;
    #pragma unroll
    for (int off = 32; off; off >>= 1) var2 += __shfl_xor(var2, off);
    var2 *= (1.f/64.f);
    float y = dv2 * rsqrtf(var2 + EPSF) * ln2w[d] + ln2b[d];

    const int kg = kg_off + k;
    float* po = out + ((size_t)b * 1024 + kg) * 128;
    po[d]      = y;
    po[64 + d] = y;   // tile (1,1,2)
}

extern "C" void kernel_launch(void* const* d_in, const int* in_sizes, int n_in,
                              void* d_out, int out_size, void* d_ws, size_t ws_size,
                              hipStream_t stream) {
    const float* x    = (const float*)d_in[0];
    const float* pe   = (const float*)d_in[1];
    const float* ct   = (const float*)d_in[2];
    const float* Wq   = (const float*)d_in[3];   // in_proj_w (192,64)
    const float* bq   = (const float*)d_in[4];   // in_proj_b (192)
    const float* Wo   = (const float*)d_in[5];   // out_proj_w (64,64)
    const float* bo   = (const float*)d_in[6];
    const float* L1w  = (const float*)d_in[7];   // (96,64)
    const float* b1   = (const float*)d_in[8];
    const float* L2w  = (const float*)d_in[9];   // (64,96)
    const float* b2   = (const float*)d_in[10];
    const float* ln1w = (const float*)d_in[11];
    const float* ln1b = (const float*)d_in[12];
    const float* ln2w = (const float*)d_in[13];
    const float* ln2b = (const float*)d_in[14];
    float* out = (float*)d_out;
    float* ws  = (float*)d_ws;

    k_pre <<<MAXP + 1, 64, 0, stream>>>(pe, ct, Wq, bq, ws);
    k_main<<<4096, 64, 0, stream>>>(x, ct, Wo, bo, L1w, b1, L2w, b2,
                                    ln1w, ln1b, ln2w, ln2b, ws, out);
}

// Round 3
// 48.886 us; speedup vs baseline: 1.1503x; 1.1369x over previous
//
#include <hip/hip_runtime.h>
#include <math.h>

#define MAXP 145          // real pos tokens max (n = 145)
#define PJ   148          // padded row count (mult of 4)
#define EPSF 1e-5f
#define NPAR 130048

// ---- workspace layout (floats) ----
#define WS_VPOS 0                      // [PJ][64], rows >= MAXP zeroed
#define WS_VCLS (PJ*64)                // [64]
#define WS_UV   (WS_VCLS+64)           // [64]
#define WS_BETA (WS_UV+64)             // betaT [4][152]
#define WS_ALGA (WS_BETA+4*152)        // alpha[4], gamma[4]

// K1: blocks 0..144 -> vpos row j, betaT[.][j]; block 145 -> vcls, uv, alpha, gamma, zero rows
__global__ __launch_bounds__(64) void k_pre(const float* __restrict__ pe,
                                            const float* __restrict__ ct,
                                            const float* __restrict__ W,   // in_proj_w (192,64)
                                            const float* __restrict__ bq,  // in_proj_b (192)
                                            float* __restrict__ ws)
{
    const int j = blockIdx.x;
    const int o = threadIdx.x;   // 0..63
    const float4* wq4 = (const float4*)(W + o*64);
    const float4* wk4 = (const float4*)(W + (64 + o)*64);
    const float4* wv4 = (const float4*)(W + (128 + o)*64);
    const float4* ct4 = (const float4*)ct;

    if (j < MAXP) {
        const float4* p4 = (const float4*)(pe + j*64);
        float sk = bq[64 + o], sv = bq[128 + o], sq = bq[o];
        #pragma unroll
        for (int e = 0; e < 16; ++e) {
            float4 k4 = wk4[e], v4 = wv4[e], q4 = wq4[e], pp = p4[e], cc = ct4[e];
            sk += k4.x*pp.x + k4.y*pp.y + k4.z*pp.z + k4.w*pp.w;
            sv += v4.x*pp.x + v4.y*pp.y + v4.z*pp.z + v4.w*pp.w;
            sq += q4.x*cc.x + q4.y*cc.y + q4.z*cc.z + q4.w*cc.w;
        }
        ws[WS_VPOS + j*64 + o] = sv;                      // coalesced row write
        // betaT[h][j] = sum over lanes of head h of q0[o]*kpos_j[o]
        float r = sq * sk;
        #pragma unroll
        for (int off = 1; off < 16; off <<= 1) r += __shfl_xor(r, off);
        if ((o & 15) == 0) ws[WS_BETA + (o >> 4)*152 + j] = r;
    } else {
        float sq = bq[o], sk = bq[64 + o], sv = bq[128 + o], suk = 0.f, suv = 0.f;
        #pragma unroll
        for (int e = 0; e < 16; ++e) {
            float4 k4 = wk4[e], v4 = wv4[e], q4 = wq4[e], cc = ct4[e];
            sq += q4.x*cc.x + q4.y*cc.y + q4.z*cc.z + q4.w*cc.w;
            sk += k4.x*cc.x + k4.y*cc.y + k4.z*cc.z + k4.w*cc.w;
            sv += v4.x*cc.x + v4.y*cc.y + v4.z*cc.z + v4.w*cc.w;
            suk += k4.x + k4.y + k4.z + k4.w;
            suv += v4.x + v4.y + v4.z + v4.w;
        }
        ws[WS_VCLS + o] = sv;
        ws[WS_UV + o]   = suv;
        // zero padding rows of vpos
        for (int r = MAXP; r < PJ; ++r) ws[WS_VPOS + r*64 + o] = 0.f;
        float a = sq * suk, g = sq * sk;
        #pragma unroll
        for (int off = 1; off < 16; off <<= 1) {
            a += __shfl_xor(a, off);
            g += __shfl_xor(g, off);
        }
        if ((o & 15) == 0) { ws[WS_ALGA + (o >> 4)] = a; ws[WS_ALGA + 4 + (o >> 4)] = g; }
    }
}

// K2: 256 threads = 4 waves, each wave = one sequence. 1024 blocks.
__global__ __launch_bounds__(256) void k_main(
    const float* __restrict__ x,
    const float* __restrict__ ct,
    const float* __restrict__ Wo,  const float* __restrict__ bo,
    const float* __restrict__ L1w, const float* __restrict__ b1,
    const float* __restrict__ L2w, const float* __restrict__ b2,
    const float* __restrict__ ln1w, const float* __restrict__ ln1b,
    const float* __restrict__ ln2w, const float* __restrict__ ln2b,
    const float* __restrict__ ws,
    float* __restrict__ out)
{
    const float* vpos  = ws + WS_VPOS;
    const float* vcls  = ws + WS_VCLS;
    const float* uv    = ws + WS_UV;
    const float* betaT = ws + WS_BETA;
    const float* alga  = ws + WS_ALGA;

    const int wave = threadIdx.x >> 6;
    const int lane = threadIdx.x & 63;

    const int bid = blockIdx.x;
    int start, L, kno, kg_off, b, k;
    if (bid < 256)      { int g = bid*4 + wave;        start = 0;     L = 72;  kno = 256; kg_off = 0;   b = g >> 8; k = g & 255; }
    else if (bid < 512) { int g = (bid-256)*4 + wave;  start = 18688; L = 144; kno = 256; kg_off = 256; b = g >> 8; k = g & 255; }
    else                { int g = (bid-512)*4 + wave;  start = 55808; L = 144; kno = 512; kg_off = 512; b = g >> 9; k = g & 511; }
    const int n  = L + 1;        // non-cls tokens
    const int S  = n + 1;        // sequence length incl. cls
    const int n4 = (n + 3) >> 2;
    const int ns = (S + 15) >> 4;   // score slots per lane (<=10)

    __shared__ float w_s [4][PJ];
    __shared__ float att2[4][4][PJ];   // [wave][head][j] normalized, shifted, padded
    __shared__ float sc4 [4][8];       // [wave][0..3]=a0, [4..7]=wsum
    __shared__ float o_s [4][64];
    __shared__ float h1_s[4][64];
    __shared__ float r_s [4][96];

    const float* xb = x + (size_t)b * NPAR;

    // scalar params w[0..L-1] + bias -> w_s (per wave)
    if (lane * 4 < L) {
        float4 v = *(const float4*)(xb + start + (size_t)k * L + lane*4);
        *(float4*)(&w_s[wave][lane*4]) = v;
    }
    if (lane == 0) w_s[wave][L] = xb[start + (size_t)kno * L + k];
    __syncthreads();

    // ---- head-parallel scores + softmax in registers ----
    const int e = lane & 15;         // lane within head
    const int h = lane >> 4;         // head
    const float alpha = alga[h];
    const float gam   = alga[4 + h];
    const float* bh   = betaT + h*152;

    float p[10];
    float m = -1e30f;
    #pragma unroll 10
    for (int t = 0; t < ns; ++t) {
        const int s = e + 16*t;
        float v = -1e30f;
        if (s < S) {
            v = (s == 0) ? gam : fmaf(alpha, w_s[wave][s-1], bh[s-1]);
            v *= 0.25f;
        }
        p[t] = v;
        m = fmaxf(m, v);
    }
    #pragma unroll
    for (int off = 1; off < 16; off <<= 1) m = fmaxf(m, __shfl_xor(m, off));

    float sum = 0.f;
    #pragma unroll 10
    for (int t = 0; t < ns; ++t) {
        const int s = e + 16*t;
        if (s < S) { float ex = __expf(p[t] - m); p[t] = ex; sum += ex; }
    }
    #pragma unroll
    for (int off = 1; off < 16; off <<= 1) sum += __shfl_xor(sum, off);
    const float inv = 1.f / sum;

    float wsl = 0.f;
    #pragma unroll 10
    for (int t = 0; t < ns; ++t) {
        const int s = e + 16*t;
        if (s < S) {
            float a = p[t] * inv;
            if (s == 0) sc4[wave][h] = a;
            else {
                att2[wave][h][s-1] = a;
                wsl += a * w_s[wave][s-1];
            }
        }
    }
    #pragma unroll
    for (int off = 1; off < 16; off <<= 1) wsl += __shfl_xor(wsl, off);
    if (e == 0) sc4[wave][4 + h] = wsl;
    { int jj = n + e; if (jj < n4*4) att2[wave][h][jj] = 0.f; }
    __syncthreads();

    // ---- o[d] = wsum*uv + a0*vcls + sum_j a[j]*vpos[j][d]  (coalesced) ----
    const int d  = lane;
    const int hd = d >> 4;
    {
        const float a0   = sc4[wave][hd];
        const float wsum = sc4[wave][4 + hd];
        const float4* arow = (const float4*)att2[wave][hd];
        float a0c = 0.f, a1c = 0.f, a2c = 0.f, a3c = 0.f;
        for (int t = 0; t < n4; ++t) {
            float4 a = arow[t];
            const float* vp = vpos + t*256 + d;
            a0c += a.x * vp[0];
            a1c += a.y * vp[64];
            a2c += a.z * vp[128];
            a3c += a.w * vp[192];
        }
        o_s[wave][d] = (a0c + a1c) + (a2c + a3c) + wsum*uv[d] + a0*vcls[d];
    }
    __syncthreads();

    // ---- out proj + residual(cls) + LN1 ----
    float op = bo[d];
    {
        const float4* wr = (const float4*)(Wo + d*64);
        const float4* os = (const float4*)o_s[wave];
        float ax=0, ay=0, az=0, aw=0;
        #pragma unroll
        for (int t = 0; t < 16; ++t) {
            float4 w4 = wr[t], o4 = os[t];
            ax += w4.x*o4.x; ay += w4.y*o4.y; az += w4.z*o4.z; aw += w4.w*o4.w;
        }
        op += (ax + ay) + (az + aw);
    }
    float pre = ct[d] + op;
    float mu = pre;
    #pragma unroll
    for (int off = 32; off; off >>= 1) mu += __shfl_xor(mu, off);
    mu *= (1.f/64.f);
    float dv = pre - mu;
    float var = dv*dv;
    #pragma unroll
    for (int off = 32; off; off >>= 1) var += __shfl_xor(var, off);
    var *= (1.f/64.f);
    float h1 = dv * rsqrtf(var + EPSF) * ln1w[d] + ln1b[d];
    h1_s[wave][d] = h1;
    __syncthreads();

    // ---- FF1 (96 outputs) + relu ----
    {
        const float4* hv = (const float4*)h1_s[wave];
        {
            const float4* r1 = (const float4*)(L1w + lane*64);
            float ax=0, ay=0, az=0, aw=0;
            #pragma unroll
            for (int t = 0; t < 16; ++t) {
                float4 w4 = r1[t], h4 = hv[t];
                ax += w4.x*h4.x; ay += w4.y*h4.y; az += w4.z*h4.z; aw += w4.w*h4.w;
            }
            r_s[wave][lane] = fmaxf(b1[lane] + (ax+ay) + (az+aw), 0.f);
        }
        if (lane < 32) {
            const float4* r1 = (const float4*)(L1w + (64 + lane)*64);
            float ax=0, ay=0, az=0, aw=0;
            #pragma unroll
            for (int t = 0; t < 16; ++t) {
                float4 w4 = r1[t], h4 = hv[t];
                ax += w4.x*h4.x; ay += w4.y*h4.y; az += w4.z*h4.z; aw += w4.w*h4.w;
            }
            r_s[wave][64 + lane] = fmaxf(b1[64 + lane] + (ax+ay) + (az+aw), 0.f);
        }
    }
    __syncthreads();

    // ---- FF2 + residual + LN2 ----
    float f2 = b2[d];
    {
        const float4* r2 = (const float4*)(L2w + d*96);
        const float4* rv = (const float4*)r_s[wave];
        float ax=0, ay=0, az=0, aw=0;
        #pragma unroll
        for (int t = 0; t < 24; ++t) {
            float4 w4 = r2[t], h4 = rv[t];
            ax += w4.x*h4.x; ay += w4.y*h4.y; az += w4.z*h4.z; aw += w4.w*h4.w;
        }
        f2 += (ax + ay) + (az + aw);
    }
    float pre2 = h1 + f2;
    float mu2 = pre2;
    #pragma unroll
    for (int off = 32; off; off >>= 1) mu2 += __shfl_xor(mu2, off);
    mu2 *= (1.f/64.f);
    float dv2 = pre2 - mu2;
    float var2 = dv2*dv2;
    #pragma unroll
    for (int off = 32; off; off >>= 1) var2 += __shfl_xor(var2, off);
    var2 *= (1.f/64.f);
    float y = dv2 * rsqrtf(var2 + EPSF) * ln2w[d] + ln2b[d];

    float* po = out + ((size_t)b * 1024 + kg_off + k) * 128;
    po[d]      = y;
    po[64 + d] = y;   // tile (1,1,2)
}

extern "C" void kernel_launch(void* const* d_in, const int* in_sizes, int n_in,
                              void* d_out, int out_size, void* d_ws, size_t ws_size,
                              hipStream_t stream) {
    const float* x    = (const float*)d_in[0];
    const float* pe   = (const float*)d_in[1];
    const float* ct   = (const float*)d_in[2];
    const float* Wq   = (const float*)d_in[3];
    const float* bq   = (const float*)d_in[4];
    const float* Wo   = (const float*)d_in[5];
    const float* bo   = (const float*)d_in[6];
    const float* L1w  = (const float*)d_in[7];
    const float* b1   = (const float*)d_in[8];
    const float* L2w  = (const float*)d_in[9];
    const float* b2   = (const float*)d_in[10];
    const float* ln1w = (const float*)d_in[11];
    const float* ln1b = (const float*)d_in[12];
    const float* ln2w = (const float*)d_in[13];
    const float* ln2b = (const float*)d_in[14];
    float* out = (float*)d_out;
    float* ws  = (float*)d_ws;

    k_pre <<<MAXP + 1, 64, 0, stream>>>(pe, ct, Wq, bq, ws);
    k_main<<<1024, 256, 0, stream>>>(x, ct, Wo, bo, L1w, b1, L2w, b2,
                                     ln1w, ln1b, ln2w, ln2b, ws, out);
}